// Round 19
// baseline (230.130 us; speedup 1.0000x reference)
//
#include <hip/hip_runtime.h>
#include <cstdint>

#define NB 4
#define NN 4096
#define LL 256
#define KTOP 20
#define EPSF 1e-6f
#define CSPLIT 4
#define NCAND (CSPLIT * KTOP)   // 80
#define KD 512          // storage: [hi(256) | lo(256)] fp16 per row

typedef _Float16 f16x8 __attribute__((ext_vector_type(8)));
typedef _Float16 f16x4 __attribute__((ext_vector_type(4)));
typedef float f32x16 __attribute__((ext_vector_type(16)));
typedef float f32x4 __attribute__((ext_vector_type(4)));   // clang vector: ok for nontemporal builtins

// ---------------- Kernel 0: per-row stats + fp16 hi/lo split ----------------
__global__ __launch_bounds__(64) void stats_split(const float* __restrict__ hist,
                                                  _Float16* __restrict__ xd) {
    int row = blockIdx.x;              // 0 .. B*N-1
    int lane = threadIdx.x;            // 0 .. 63
    float4 v = reinterpret_cast<const float4*>(hist + (size_t)row * LL)[lane];
    float s = v.x + v.y + v.z + v.w;
    #pragma unroll
    for (int off = 32; off; off >>= 1) s += __shfl_xor(s, off);
    float mean = s * (1.0f / 256.0f);
    float c0 = v.x - mean, c1 = v.y - mean, c2 = v.z - mean, c3 = v.w - mean;
    float ss = c0*c0 + c1*c1 + c2*c2 + c3*c3;
    #pragma unroll
    for (int off = 32; off; off >>= 1) ss += __shfl_xor(ss, off);
    float inv = 1.0f / fmaxf(sqrtf(ss * (1.0f / 256.0f)), EPSF);
    float n0 = c0*inv, n1 = c1*inv, n2 = c2*inv, n3 = c3*inv;
    f16x4 h, lo;
    h[0] = (_Float16)n0; h[1] = (_Float16)n1; h[2] = (_Float16)n2; h[3] = (_Float16)n3;
    lo[0] = (_Float16)(n0 - (float)h[0]);
    lo[1] = (_Float16)(n1 - (float)h[1]);
    lo[2] = (_Float16)(n2 - (float)h[2]);
    lo[3] = (_Float16)(n3 - (float)h[3]);
    _Float16* base = xd + (size_t)row * KD + lane * 4;
    *(f16x4*)base = h;
    *(f16x4*)(base + 256) = lo;
}

// ------- Kernel 1: fp16 split-product MFMA GEMM (swapped operands) + top-20 -------
// = round 18 (verified) + tile-level lookahead: scratch moved As0->As1
// (As1's last reader = MFMA(q3), fenced by the q3 barrier); next tile's
// A(q0)->As0 and B(q0)->Bs issued right after the q3 barrier so the 48 KB
// flight rides under zero-fill + selection + insert. The tile-top barrier's
// implicit vmcnt(0) is the drain -> per-tile prologue stage+drain (16 fully
// exposed flights + 16 barriers) eliminated.
// dot = hi.hi' + hi.lo' + lo.hi' (fp32-parity). Block: 256 thr (4 waves),
// 128 rows, 1024 cols (CSPLIT=4), col-tiles of 64 (acc[2]; acc[4] spilled r12).
// Intra-tile: A(q+1)->As[alt] issued before MFMA(q); B(q+1) staged after the
// post-MFMA barrier (Bs single-buffered). As x2 + Bs = 80 KB (2 blocks/CU).
// SWAPPED MFMA: acc[j][rg] = sim[row=lane&31][col=j*32+(rg&3)+8*(rg>>2)+
// 4*(lane>>5)] -- lane owns its half-row in registers. Candidates mirrored
// to lane-private LDS in As1 (addr = 32768+w*8192+l*128+((r^cb)<<2)).
// Screen thr = max(own k19, partner k19) -- merged-20th >= both, exact.
// Background zero-fill of out via nt stores (f32x4; HIP float4 rejected r16).
// NOTE launch_bounds(256,2): (256,4) capped VGPR at 64 -> spill (rounds 5,7).
__global__ __launch_bounds__(256, 2) void gemm_topk(const _Float16* __restrict__ xd,
                                                    float* __restrict__ listv,
                                                    short* __restrict__ listi,
                                                    float* __restrict__ out) {
    __shared__ __align__(16) char smem[81920];
    // As[0] = smem, As[1] = smem+32768 (32 KB each), Bs = smem+65536 (16 KB)
    char* Bs = smem + 65536;

    const int tid = threadIdx.x;
    const int w = tid >> 6;
    const int l = tid & 63;
    const int h = l >> 5;                       // col-interleave half (lane>>5)
    const int r = l & 31;                       // owned row (wave-local)

    // lane-private candidate buffer in As[1] (free after the q3 barrier)
    const unsigned vb = 32768u + ((unsigned)w << 13) + ((unsigned)l << 7);

    // XCD-chunked swizzle (grid 512, %8==0 -> bijective)
    const int phys = blockIdx.x;
    const int bid = (phys & 7) * 64 + (phys >> 3);
    const int cs = bid & 3;
    const int rowblk = (bid >> 2) & 31;
    const int b = bid >> 7;
    const int r0 = rowblk * 128;
    const size_t nbase = (size_t)b * NN;
    const _Float16* xb = xd + nbase * KD;

    // background-zero slice: 512 blocks x 32768 float4 = full 268 MB out
    f32x4* zslice = reinterpret_cast<f32x4*>(out) + (size_t)phys * 32768;

    double k[KTOP];
    #pragma unroll
    for (int q = 0; q < KTOP; ++q) k[q] = -1.0;  // value-part -1.875f: all v>=0 pass

    // staging lane constants: 1KB instr = 4 rows/cols x 256 B [hi|lo]
    const int s7 = l & 7;
    const int half8 = (l >> 3) & 1;             // hi(0)/lo(1) 128B slot
    const int quad = l >> 4;                    // row/col within the 4 per instr
    // fragment lane constants
    const int r7 = l & 7;
    const int aRowOff = (w * 32 + r) * 256;
    const int grow = r0 + w * 32 + r;           // this lane's sim row

    f32x16 acc[2];

    // one-time prologue: stage A(q0)->As0, B(ct=0,q0)->Bs
    #pragma unroll
    for (int s = 0; s < 8; ++s) {
        const int i = w * 8 + s;
        const int row = i * 4 + quad;
        const _Float16* ga = xb + (size_t)(r0 + row) * KD
                           + half8 * 256 + ((s7 ^ (row & 7)) << 3);
        __builtin_amdgcn_global_load_lds(
            (const __attribute__((address_space(1))) void*)ga,
            (__attribute__((address_space(3))) void*)(smem + i * 1024), 16, 0, 0);
    }
    #pragma unroll
    for (int s = 0; s < 4; ++s) {
        const int i = w * 4 + s;
        const int col = i * 4 + quad;
        const _Float16* gb = xb + (size_t)(cs * 1024 + col) * KD
                           + half8 * 256 + ((s7 ^ (col & 7)) << 3);
        __builtin_amdgcn_global_load_lds(
            (const __attribute__((address_space(1))) void*)gb,
            (__attribute__((address_space(3))) void*)(Bs + i * 1024), 16, 0, 0);
    }

    #pragma unroll 1
    for (int ct = 0; ct < 16; ++ct) {           // 16 col-tiles of 64
        const int c0 = cs * 1024 + ct * 64;
        #pragma unroll
        for (int j = 0; j < 2; ++j)
            #pragma unroll
            for (int e = 0; e < 16; ++e) acc[j][e] = 0.0f;

        __syncthreads();   // drains prefetched A(q0)/B(q0); scratch readers done

        #pragma unroll
        for (int q = 0; q < 4; ++q) {           // 4 k-quarters of 64
            char* curA = smem + ((q & 1) << 15);
            // issue A(q+1) -> As[alt] (alt's last reader finished pre-drain)
            if (q < 3) {
                char* nxtA = smem + (((q + 1) & 1) << 15);
                #pragma unroll
                for (int s = 0; s < 8; ++s) {
                    const int i = w * 8 + s;
                    const int row = i * 4 + quad;
                    const _Float16* ga = xb + (size_t)(r0 + row) * KD
                                       + half8 * 256 + (q + 1) * 64 + ((s7 ^ (row & 7)) << 3);
                    __builtin_amdgcn_global_load_lds(
                        (const __attribute__((address_space(1))) void*)ga,
                        (__attribute__((address_space(3))) void*)(nxtA + i * 1024), 16, 0, 0);
                }
            }
            __builtin_amdgcn_s_setprio(1);
            #pragma unroll
            for (int ks = 0; ks < 4; ++ks) {    // 24 MFMA per quarter
                const int koff = ((ks * 2 + h) ^ r7) << 4;
                const char* aRow = curA + aRowOff;
                f16x8 ah = *(const f16x8*)(aRow + koff);
                f16x8 al = *(const f16x8*)(aRow + 128 + koff);
                #pragma unroll
                for (int j = 0; j < 2; ++j) {
                    const char* bR = Bs + (j * 32 + r) * 256;
                    f16x8 bh = *(const f16x8*)(bR + koff);
                    f16x8 bl = *(const f16x8*)(bR + 128 + koff);
                    acc[j] = __builtin_amdgcn_mfma_f32_32x32x16_f16(bh, ah, acc[j], 0, 0, 0);
                    acc[j] = __builtin_amdgcn_mfma_f32_32x32x16_f16(bh, al, acc[j], 0, 0, 0);
                    acc[j] = __builtin_amdgcn_mfma_f32_32x32x16_f16(bl, ah, acc[j], 0, 0, 0);
                }
            }
            __builtin_amdgcn_s_setprio(0);
            __syncthreads();                    // MFMA(q) readers done (Bs free)
            if (q < 3) {
                #pragma unroll
                for (int s = 0; s < 4; ++s) {   // stage B(q+1) -> Bs
                    const int i = w * 4 + s;
                    const int col = i * 4 + quad;
                    const _Float16* gb = xb + (size_t)(c0 + col) * KD
                                       + half8 * 256 + (q + 1) * 64 + ((s7 ^ (col & 7)) << 3);
                    __builtin_amdgcn_global_load_lds(
                        (const __attribute__((address_space(1))) void*)gb,
                        (__attribute__((address_space(3))) void*)(Bs + i * 1024), 16, 0, 0);
                }
                __syncthreads();                // drain A(q+1)+B(q+1)
            }
        }
        // post-q3 barrier reached: As0 free (last read MFMA q2), Bs free,
        // As1 = selection scratch (last read MFMA q3, fenced).

        // ---- prefetch next tile's A(q0)->As0 and B(q0)->Bs ----
        if (ct < 15) {
            const int c0n = c0 + 64;
            #pragma unroll
            for (int s = 0; s < 8; ++s) {
                const int i = w * 8 + s;
                const int row = i * 4 + quad;
                const _Float16* ga = xb + (size_t)(r0 + row) * KD
                                   + half8 * 256 + ((s7 ^ (row & 7)) << 3);
                __builtin_amdgcn_global_load_lds(
                    (const __attribute__((address_space(1))) void*)ga,
                    (__attribute__((address_space(3))) void*)(smem + i * 1024), 16, 0, 0);
            }
            #pragma unroll
            for (int s = 0; s < 4; ++s) {
                const int i = w * 4 + s;
                const int col = i * 4 + quad;
                const _Float16* gb = xb + (size_t)(c0n + col) * KD
                                   + half8 * 256 + ((s7 ^ (col & 7)) << 3);
                __builtin_amdgcn_global_load_lds(
                    (const __attribute__((address_space(1))) void*)gb,
                    (__attribute__((address_space(3))) void*)(Bs + i * 1024), 16, 0, 0);
            }
        }

        // ---- background zero of this block's out slice (nt stores, 8 KB/wave) ----
        {
            const f32x4 z4 = {0.f, 0.f, 0.f, 0.f};
            f32x4* ob = zslice + ct * 2048 + tid;
            #pragma unroll
            for (int i = 0; i < 8; ++i)
                __builtin_nontemporal_store(z4, ob + i * 256);
        }

        // ---- selection sweep straight from registers (rows are lane-local) ----
        const float myk19 = __int_as_float(__double2hiint(k[KTOP - 1]));
        const float thr = fmaxf(myk19, __shfl_xor(myk19, 32));
        unsigned int m = 0u;
        #pragma unroll
        for (int j = 0; j < 2; ++j) {
            #pragma unroll
            for (int rg = 0; rg < 16; ++rg) {
                const int cb = j * 16 + rg;
                float v = fmaxf(acc[j][rg] * (1.0f / 256.0f), 0.0f);
                const int gcol = c0 + j * 32 + (rg & 3) + (rg >> 2) * 8 + 4 * h;
                v = (gcol == grow) ? 0.0f : v;   // zero diagonal
                *reinterpret_cast<float*>(smem + vb + (unsigned)((r ^ cb) << 2)) = v;
                m |= (v >= thr) ? (1u << cb) : 0u;
            }
        }
        // ---- ballot-compacted exact f64 sorted-key insert ----
        while (__ballot(m != 0u)) {
            const bool act = (m != 0u);
            int cb = __ffs(m) - 1;
            cb = act ? cb : 0;
            m &= m - 1;
            const float v = *reinterpret_cast<const float*>(smem + vb + (unsigned)((r ^ cb) << 2));
            const int gcol = c0 + ((cb >> 4) << 5) + (cb & 3) + ((cb >> 2) & 3) * 8 + 4 * h;
            const double key = act ? __hiloint2double(__float_as_int(v), 4095 - gcol)
                                   : -2.0;       // -2 < all keys incl. init: no-op
            #pragma unroll
            for (int q = KTOP - 1; q > 0; --q)
                k[q] = fmax(k[q], fmin(k[q - 1], key));
            k[0] = fmax(k[0], key);
        }
    }

    // ---- merge the two half-row lists by rank, write top-20 per (row, split) ----
    int cnt[KTOP];
    #pragma unroll
    for (int p = 0; p < KTOP; ++p) cnt[p] = 0;
    #pragma unroll
    for (int q = 0; q < KTOP; ++q) {
        int phi = __shfl_xor(__double2hiint(k[q]), 32);
        int plo = __shfl_xor(__double2loint(k[q]), 32);
        double pk = __hiloint2double(phi, plo);
        #pragma unroll
        for (int p = 0; p < KTOP; ++p) cnt[p] += (pk > k[p]) ? 1 : 0;
    }
    size_t base = ((nbase + r0 + w * 32 + r) * CSPLIT + cs) * KTOP;
    #pragma unroll
    for (int p = 0; p < KTOP; ++p) {
        int rank = p + cnt[p];
        if (rank < KTOP) {
            int hi = __double2hiint(k[p]);
            int lo = __double2loint(k[p]);
            listv[base + rank] = fmaxf(__int_as_float(hi), 0.0f);  // unfilled -> 0
            listi[base + rank] = (short)(4095 - lo);
        }
    }
}

// ------- Kernel 2: 4-way rank-merge + double row-normalize + scatter-only -------
// (output zeroing lives in gemm_topk as overlapped nt stores)
__global__ __launch_bounds__(256) void merge_kernel(const float* __restrict__ listv,
                                                    const short* __restrict__ listi,
                                                    float* __restrict__ out) {
    __shared__ float ldsv[4][NCAND];
    __shared__ int   ldsi[4][NCAND];
    __shared__ float selv[4][KTOP];
    __shared__ int   seli[4][KTOP];
    const int tid = threadIdx.x;
    const int wv = tid >> 6;
    const int l = tid & 63;
    const size_t gr = (size_t)blockIdx.x * 4 + wv;    // global row 0..16383

    ldsv[wv][l] = listv[gr * NCAND + l];
    ldsi[wv][l] = (int)listi[gr * NCAND + l];
    if (l < 16) {
        ldsv[wv][64 + l] = listv[gr * NCAND + 64 + l];
        ldsi[wv][64 + l] = (int)listi[gr * NCAND + 64 + l];
    }
    __syncthreads();

    // rank-select top-20 of 80: strict total order (val desc, idx asc, slot asc)
    const int q0 = l, q1 = 64 + l;              // q1 valid for l < 16
    float v0 = ldsv[wv][q0];                 int i0 = ldsi[wv][q0];
    float v1 = (l < 16) ? ldsv[wv][q1] : -2.0f;
    int   i1 = (l < 16) ? ldsi[wv][q1] : 0x7fffffff;
    int rank0 = 0, rank1 = 0;
    for (int p = 0; p < NCAND; ++p) {
        float vp = ldsv[wv][p]; int ip = ldsi[wv][p];
        rank0 += ((vp > v0) || (vp == v0 && (ip < i0 || (ip == i0 && p < q0)))) ? 1 : 0;
        rank1 += ((vp > v1) || (vp == v1 && (ip < i1 || (ip == i1 && p < q1)))) ? 1 : 0;
    }
    if (rank0 < KTOP) { selv[wv][rank0] = v0; seli[wv][rank0] = i0; }
    if (l < 16 && rank1 < KTOP) { selv[wv][rank1] = v1; seli[wv][rank1] = i1; }
    __syncthreads();

    // double row-normalize (matches reference: /max(sum,eps) twice)
    float wval = (l < KTOP) ? selv[wv][l] : 0.0f;
    int   widx = (l < KTOP) ? seli[wv][l] : -1;
    float s1 = wval;
    #pragma unroll
    for (int off = 32; off; off >>= 1) s1 += __shfl_xor(s1, off);
    float w1 = wval / fmaxf(s1, EPSF);
    float s2 = (l < KTOP) ? w1 : 0.0f;
    #pragma unroll
    for (int off = 32; off; off >>= 1) s2 += __shfl_xor(s2, off);
    float wf = w1 / fmaxf(s2, EPSF);

    if (l < KTOP && widx >= 0 && wval > 0.0f) out[gr * NN + widx] = wf;
}

extern "C" void kernel_launch(void* const* d_in, const int* in_sizes, int n_in,
                              void* d_out, int out_size, void* d_ws, size_t ws_size,
                              hipStream_t stream) {
    const float* hist = (const float*)d_in[0];
    // d_in[1] = mask [B,N] — all ones in this problem; ignored.
    char* ws = (char*)d_ws;
    const size_t xdBytes = (size_t)NB * NN * KD * sizeof(_Float16);        // 16.78 MB
    const size_t lvBytes = (size_t)NB * NN * NCAND * sizeof(float);        // 5.24 MB
    _Float16* xd = (_Float16*)ws;
    float* listv = (float*)(ws + xdBytes);
    short* listi = (short*)(ws + xdBytes + lvBytes);                        // 2.62 MB
    float* out = (float*)d_out;

    stats_split<<<NB * NN, 64, 0, stream>>>(hist, xd);
    gemm_topk<<<NB * 32 * CSPLIT, 256, 0, stream>>>(xd, listv, listi, out);
    merge_kernel<<<NB * NN / 4, 256, 0, stream>>>(listv, listi, out);
}

// Round 20
// 228.372 us; speedup vs baseline: 1.0077x; 1.0077x over previous
//
#include <hip/hip_runtime.h>
#include <cstdint>

#define NB 4
#define NN 4096
#define LL 256
#define KTOP 20
#define EPSF 1e-6f
#define CSPLIT 4
#define NCAND (CSPLIT * KTOP)   // 80
#define KD 512          // storage: [hi(256) | lo(256)] fp16 per row

typedef _Float16 f16x8 __attribute__((ext_vector_type(8)));
typedef _Float16 f16x4 __attribute__((ext_vector_type(4)));
typedef float f32x16 __attribute__((ext_vector_type(16)));
typedef float f32x4 __attribute__((ext_vector_type(4)));   // clang vector: ok for nontemporal builtins

// ---------------- Kernel 0: per-row stats + fp16 hi/lo split ----------------
__global__ __launch_bounds__(64) void stats_split(const float* __restrict__ hist,
                                                  _Float16* __restrict__ xd) {
    int row = blockIdx.x;              // 0 .. B*N-1
    int lane = threadIdx.x;            // 0 .. 63
    float4 v = reinterpret_cast<const float4*>(hist + (size_t)row * LL)[lane];
    float s = v.x + v.y + v.z + v.w;
    #pragma unroll
    for (int off = 32; off; off >>= 1) s += __shfl_xor(s, off);
    float mean = s * (1.0f / 256.0f);
    float c0 = v.x - mean, c1 = v.y - mean, c2 = v.z - mean, c3 = v.w - mean;
    float ss = c0*c0 + c1*c1 + c2*c2 + c3*c3;
    #pragma unroll
    for (int off = 32; off; off >>= 1) ss += __shfl_xor(ss, off);
    float inv = 1.0f / fmaxf(sqrtf(ss * (1.0f / 256.0f)), EPSF);
    float n0 = c0*inv, n1 = c1*inv, n2 = c2*inv, n3 = c3*inv;
    f16x4 h, lo;
    h[0] = (_Float16)n0; h[1] = (_Float16)n1; h[2] = (_Float16)n2; h[3] = (_Float16)n3;
    lo[0] = (_Float16)(n0 - (float)h[0]);
    lo[1] = (_Float16)(n1 - (float)h[1]);
    lo[2] = (_Float16)(n2 - (float)h[2]);
    lo[3] = (_Float16)(n3 - (float)h[3]);
    _Float16* base = xd + (size_t)row * KD + lane * 4;
    *(f16x4*)base = h;
    *(f16x4*)(base + 256) = lo;
}

// ------- Kernel 1: fp16 split-product MFMA GEMM (swapped operands) + top-20 -------
// FINAL = round 17 config (session best: 228.6us total, gemm 209.6us).
// Rounds 18/19 (A-double-buffer, tile lookahead) both measured neutral:
// at 2 blocks/CU, implicit wave-level overlap already hides intra-tile
// staging, and every __syncthreads drains vmcnt(0) (guide m99/m131-140).
// dot = hi.hi' + hi.lo' + lo.hi' (fp32-parity; lo.lo' ~ 2^-22 dropped).
// Block: 256 thr (4 waves), 128 rows, 1024 cols (CSPLIT=4), col-tiles of 64
// (acc[2] = 32 AGPR; acc[4] spilled, round 12).
// JOINT staging: per k-quarter As (128r x [hi|lo] = 32 KB) + Bs (64c x
// [hi|lo] = 16 KB) in ONE phase -> 2 barriers + 1 drain per quarter.
// SWAPPED MFMA: mfma(bfrag, afrag) computes sim^T so acc[j][rg] =
// sim[row=lane&31][col=j*32+(rg&3)+8*(rg>>2)+4*(lane>>5)] -- each lane owns
// its half-row IN REGISTERS (no LDS transpose; screen straight from regs).
// Candidates mirrored to lane-private LDS for the runtime-indexed reads in
// the compacted insert: addr = w*8192 + l*128 + ((r^cb)<<2)  (l*132 in r13
// overflowed the wave region -> adjacent-wave collision; r^cb is per-lane
// bijective and bank-spread: 32 banks x 2 lanes = free 2-way).
// Screen thr = max(own k19, partner k19): merged-20th >= both lists' 20th,
// so v < thr can never surface in the merged top-20 -- exact.
// Background zero-fill of the 268 MB output via nt stores (f32x4 ext-vector;
// HIP float4 rejected by the builtin, round 16), overlapped with selection:
// merge kernel is scatter-only (~40us of serialized HBM write removed).
// NOTE launch_bounds(256,2): (256,4) capped VGPR at 64 -> spilled acc+keys
// to scratch (rounds 5/7: 13.8 GB / 1.5 GB of spill traffic).
__global__ __launch_bounds__(256, 2) void gemm_topk(const _Float16* __restrict__ xd,
                                                    float* __restrict__ listv,
                                                    short* __restrict__ listi,
                                                    float* __restrict__ out) {
    __shared__ __align__(16) char smem[49152];
    char* As = smem;                 // 32 KB: 128 rows x 256 B ([hi|lo] swizzled)
    char* Bs = smem + 32768;         // 16 KB:  64 cols x 256 B ([hi|lo] swizzled)

    const int tid = threadIdx.x;
    const int w = tid >> 6;
    const int l = tid & 63;
    const int h = l >> 5;                       // col-interleave half (lane>>5)
    const int r = l & 31;                       // owned row (wave-local)

    // lane-private candidate buffer (aliases As; fenced by quarter-top barrier)
    const unsigned vb = ((unsigned)w << 13) + ((unsigned)l << 7);

    // XCD-chunked swizzle (grid 512, %8==0 -> bijective)
    const int phys = blockIdx.x;
    const int bid = (phys & 7) * 64 + (phys >> 3);
    const int cs = bid & 3;
    const int rowblk = (bid >> 2) & 31;
    const int b = bid >> 7;
    const int r0 = rowblk * 128;
    const size_t nbase = (size_t)b * NN;
    const _Float16* xb = xd + nbase * KD;

    // background-zero slice: 512 blocks x 32768 float4 = full 268 MB out
    f32x4* zslice = reinterpret_cast<f32x4*>(out) + (size_t)phys * 32768;

    double k[KTOP];
    #pragma unroll
    for (int q = 0; q < KTOP; ++q) k[q] = -1.0;  // value-part -1.875f: all v>=0 pass

    // staging lane constants: 1KB instr = 4 rows/cols x 256 B [hi|lo]
    const int s7 = l & 7;
    const int half8 = (l >> 3) & 1;             // hi(0)/lo(1) 128B slot
    const int quad = l >> 4;                    // row/col within the 4 per instr
    // fragment lane constants
    const int r7 = l & 7;
    const char* aRow = As + (w * 32 + r) * 256;
    const int grow = r0 + w * 32 + r;           // this lane's sim row

    f32x16 acc[2];

    #pragma unroll 1
    for (int ct = 0; ct < 16; ++ct) {           // 16 col-tiles of 64
        const int c0 = cs * 1024 + ct * 64;
        #pragma unroll
        for (int j = 0; j < 2; ++j)
            #pragma unroll
            for (int e = 0; e < 16; ++e) acc[j][e] = 0.0f;

        #pragma unroll
        for (int q = 0; q < 4; ++q) {           // 4 k-quarters of 64
            __syncthreads();                    // prior readers of As/Bs/scratch done
            // stage A quarter q, both halves: 32 instrs of 1KB, 8/wave
            #pragma unroll
            for (int s = 0; s < 8; ++s) {
                const int i = w * 8 + s;
                const int row = i * 4 + quad;
                const _Float16* ga = xb + (size_t)(r0 + row) * KD
                                   + half8 * 256 + q * 64 + ((s7 ^ (row & 7)) << 3);
                __builtin_amdgcn_global_load_lds(
                    (const __attribute__((address_space(1))) void*)ga,
                    (__attribute__((address_space(3))) void*)(As + i * 1024), 16, 0, 0);
            }
            // stage B quarter q, both halves: 16 instrs of 1KB, 4/wave
            #pragma unroll
            for (int s = 0; s < 4; ++s) {
                const int i = w * 4 + s;
                const int col = i * 4 + quad;
                const _Float16* gb = xb + (size_t)(c0 + col) * KD
                                   + half8 * 256 + q * 64 + ((s7 ^ (col & 7)) << 3);
                __builtin_amdgcn_global_load_lds(
                    (const __attribute__((address_space(1))) void*)gb,
                    (__attribute__((address_space(3))) void*)(Bs + i * 1024), 16, 0, 0);
            }
            __syncthreads();                    // single drain: all 48 loads ready
            __builtin_amdgcn_s_setprio(1);
            #pragma unroll
            for (int ks = 0; ks < 4; ++ks) {    // 24 MFMA per quarter
                const int koff = ((ks * 2 + h) ^ r7) << 4;
                f16x8 ah = *(const f16x8*)(aRow + koff);
                f16x8 al = *(const f16x8*)(aRow + 128 + koff);
                #pragma unroll
                for (int j = 0; j < 2; ++j) {
                    const char* bR = Bs + (j * 32 + r) * 256;
                    f16x8 bh = *(const f16x8*)(bR + koff);
                    f16x8 bl = *(const f16x8*)(bR + 128 + koff);
                    acc[j] = __builtin_amdgcn_mfma_f32_32x32x16_f16(bh, ah, acc[j], 0, 0, 0);
                    acc[j] = __builtin_amdgcn_mfma_f32_32x32x16_f16(bh, al, acc[j], 0, 0, 0);
                    acc[j] = __builtin_amdgcn_mfma_f32_32x32x16_f16(bl, ah, acc[j], 0, 0, 0);
                }
            }
            __builtin_amdgcn_s_setprio(0);
        }

        __syncthreads();   // all waves' MFMA reads of As/Bs done; scratch may overwrite

        // ---- background zero of this block's out slice (nt stores, 8 KB/wave) ----
        {
            const f32x4 z4 = {0.f, 0.f, 0.f, 0.f};
            f32x4* ob = zslice + ct * 2048 + tid;
            #pragma unroll
            for (int i = 0; i < 8; ++i)
                __builtin_nontemporal_store(z4, ob + i * 256);
        }

        // ---- selection sweep straight from registers (rows are lane-local) ----
        const float myk19 = __int_as_float(__double2hiint(k[KTOP - 1]));
        const float thr = fmaxf(myk19, __shfl_xor(myk19, 32));
        unsigned int m = 0u;
        #pragma unroll
        for (int j = 0; j < 2; ++j) {
            #pragma unroll
            for (int rg = 0; rg < 16; ++rg) {
                const int cb = j * 16 + rg;
                float v = fmaxf(acc[j][rg] * (1.0f / 256.0f), 0.0f);
                const int gcol = c0 + j * 32 + (rg & 3) + (rg >> 2) * 8 + 4 * h;
                v = (gcol == grow) ? 0.0f : v;   // zero diagonal
                *reinterpret_cast<float*>(smem + vb + (unsigned)((r ^ cb) << 2)) = v;
                m |= (v >= thr) ? (1u << cb) : 0u;
            }
        }
        // ---- ballot-compacted exact f64 sorted-key insert ----
        while (__ballot(m != 0u)) {
            const bool act = (m != 0u);
            int cb = __ffs(m) - 1;
            cb = act ? cb : 0;
            m &= m - 1;
            const float v = *reinterpret_cast<const float*>(smem + vb + (unsigned)((r ^ cb) << 2));
            const int gcol = c0 + ((cb >> 4) << 5) + (cb & 3) + ((cb >> 2) & 3) * 8 + 4 * h;
            const double key = act ? __hiloint2double(__float_as_int(v), 4095 - gcol)
                                   : -2.0;       // -2 < all keys incl. init: no-op
            #pragma unroll
            for (int q = KTOP - 1; q > 0; --q)
                k[q] = fmax(k[q], fmin(k[q - 1], key));
            k[0] = fmax(k[0], key);
        }
    }

    // ---- merge the two half-row lists by rank, write top-20 per (row, split) ----
    int cnt[KTOP];
    #pragma unroll
    for (int p = 0; p < KTOP; ++p) cnt[p] = 0;
    #pragma unroll
    for (int q = 0; q < KTOP; ++q) {
        int phi = __shfl_xor(__double2hiint(k[q]), 32);
        int plo = __shfl_xor(__double2loint(k[q]), 32);
        double pk = __hiloint2double(phi, plo);
        #pragma unroll
        for (int p = 0; p < KTOP; ++p) cnt[p] += (pk > k[p]) ? 1 : 0;
    }
    size_t base = ((nbase + r0 + w * 32 + r) * CSPLIT + cs) * KTOP;
    #pragma unroll
    for (int p = 0; p < KTOP; ++p) {
        int rank = p + cnt[p];
        if (rank < KTOP) {
            int hi = __double2hiint(k[p]);
            int lo = __double2loint(k[p]);
            listv[base + rank] = fmaxf(__int_as_float(hi), 0.0f);  // unfilled -> 0
            listi[base + rank] = (short)(4095 - lo);
        }
    }
}

// ------- Kernel 2: 4-way rank-merge + double row-normalize + scatter-only -------
// (output zeroing lives in gemm_topk as overlapped nt stores)
__global__ __launch_bounds__(256) void merge_kernel(const float* __restrict__ listv,
                                                    const short* __restrict__ listi,
                                                    float* __restrict__ out) {
    __shared__ float ldsv[4][NCAND];
    __shared__ int   ldsi[4][NCAND];
    __shared__ float selv[4][KTOP];
    __shared__ int   seli[4][KTOP];
    const int tid = threadIdx.x;
    const int wv = tid >> 6;
    const int l = tid & 63;
    const size_t gr = (size_t)blockIdx.x * 4 + wv;    // global row 0..16383

    ldsv[wv][l] = listv[gr * NCAND + l];
    ldsi[wv][l] = (int)listi[gr * NCAND + l];
    if (l < 16) {
        ldsv[wv][64 + l] = listv[gr * NCAND + 64 + l];
        ldsi[wv][64 + l] = (int)listi[gr * NCAND + 64 + l];
    }
    __syncthreads();

    // rank-select top-20 of 80: strict total order (val desc, idx asc, slot asc)
    const int q0 = l, q1 = 64 + l;              // q1 valid for l < 16
    float v0 = ldsv[wv][q0];                 int i0 = ldsi[wv][q0];
    float v1 = (l < 16) ? ldsv[wv][q1] : -2.0f;
    int   i1 = (l < 16) ? ldsi[wv][q1] : 0x7fffffff;
    int rank0 = 0, rank1 = 0;
    for (int p = 0; p < NCAND; ++p) {
        float vp = ldsv[wv][p]; int ip = ldsi[wv][p];
        rank0 += ((vp > v0) || (vp == v0 && (ip < i0 || (ip == i0 && p < q0)))) ? 1 : 0;
        rank1 += ((vp > v1) || (vp == v1 && (ip < i1 || (ip == i1 && p < q1)))) ? 1 : 0;
    }
    if (rank0 < KTOP) { selv[wv][rank0] = v0; seli[wv][rank0] = i0; }
    if (l < 16 && rank1 < KTOP) { selv[wv][rank1] = v1; seli[wv][rank1] = i1; }
    __syncthreads();

    // double row-normalize (matches reference: /max(sum,eps) twice)
    float wval = (l < KTOP) ? selv[wv][l] : 0.0f;
    int   widx = (l < KTOP) ? seli[wv][l] : -1;
    float s1 = wval;
    #pragma unroll
    for (int off = 32; off; off >>= 1) s1 += __shfl_xor(s1, off);
    float w1 = wval / fmaxf(s1, EPSF);
    float s2 = (l < KTOP) ? w1 : 0.0f;
    #pragma unroll
    for (int off = 32; off; off >>= 1) s2 += __shfl_xor(s2, off);
    float wf = w1 / fmaxf(s2, EPSF);

    if (l < KTOP && widx >= 0 && wval > 0.0f) out[gr * NN + widx] = wf;
}

extern "C" void kernel_launch(void* const* d_in, const int* in_sizes, int n_in,
                              void* d_out, int out_size, void* d_ws, size_t ws_size,
                              hipStream_t stream) {
    const float* hist = (const float*)d_in[0];
    // d_in[1] = mask [B,N] — all ones in this problem; ignored.
    char* ws = (char*)d_ws;
    const size_t xdBytes = (size_t)NB * NN * KD * sizeof(_Float16);        // 16.78 MB
    const size_t lvBytes = (size_t)NB * NN * NCAND * sizeof(float);        // 5.24 MB
    _Float16* xd = (_Float16*)ws;
    float* listv = (float*)(ws + xdBytes);
    short* listi = (short*)(ws + xdBytes + lvBytes);                        // 2.62 MB
    float* out = (float*)d_out;

    stats_split<<<NB * NN, 64, 0, stream>>>(hist, xd);
    gemm_topk<<<NB * 32 * CSPLIT, 256, 0, stream>>>(xd, listv, listi, out);
    merge_kernel<<<NB * NN / 4, 256, 0, stream>>>(listv, listi, out);
}